// Round 11
// baseline (288.882 us; speedup 1.0000x reference)
//
#include <hip/hip_runtime.h>
#include <hip/hip_bf16.h>
#include <stdint.h>

// SpatialMHA: B=64 S=256 E=1024 H=16 D=64
// qkv = x @ Win^T + bin ; attn with additive spatial bias ; out = x + ctx @ Wout^T + bout

typedef __attribute__((ext_vector_type(8))) __bf16 bf16x8;
typedef __attribute__((ext_vector_type(4))) float f32x4;

#define DEVI static __device__ __forceinline__

DEVI unsigned short f2bf(float f) {           // fp32 -> bf16 round-to-nearest-even
  union { float f; unsigned u; } x; x.f = f;
  unsigned r = x.u + 0x7fffu + ((x.u >> 16) & 1u);
  return (unsigned short)(r >> 16);
}

DEVI float bf2f(unsigned short h) {
  union { unsigned u; float f; } x; x.u = (unsigned)h << 16; return x.f;
}

typedef unsigned int __attribute__((address_space(1))) u32_g;
typedef unsigned int __attribute__((address_space(3))) u32_l;

DEVI void g2l16(const unsigned short* g, unsigned short* l) {
  // async global->LDS, 16B per lane; LDS dest = wave-uniform base + lane*16
  __builtin_amdgcn_global_load_lds((const u32_g*)g, (u32_l*)l, 16, 0, 0);
}

// ---------------------------------------------------------------- fp32->bf16
__global__ __launch_bounds__(256) void cvt_kernel(const float* __restrict__ s,
                                                  unsigned short* __restrict__ d, int n) {
  int i = (blockIdx.x * 256 + threadIdx.x) * 4;
  if (i >= n) return;
  float4 v = *(const float4*)(s + i);
  ushort4 o;
  o.x = f2bf(v.x); o.y = f2bf(v.y); o.z = f2bf(v.z); o.w = f2bf(v.w);
  *(ushort4*)(d + i) = o;
}

// ---------------------------------------------------------------- 256x128 GEMM, 4 waves
// Structure unchanged since R5 (MfmaUtil ~31%, 0 conflicts, no spill).
// R10: T1 bijective XCD swizzle, column-major chunking. 1D grid; each XCD gets
// a contiguous chunk of 8 A-panels x all N-blocks: A chunk = 8 x 512KB = 4MB =
// one XCD L2, so A staging becomes L2-local after first touch (was: round-robin
// scattered same-panel blocks across XCDs -> every panel re-pulled through L3).
// GY = N-blocks (24 for gemm0, 8 for gemm1); grid must be divisible by 8.
template <int EPI, int GY>
__global__ __launch_bounds__(256, 2)
void gemm4(const unsigned short* __restrict__ A,
           const unsigned short* __restrict__ Bw,
           const float* __restrict__ bias,
           unsigned short* __restrict__ Qo,
           unsigned short* __restrict__ Ko,
           unsigned short* __restrict__ VTo,
           const float* __restrict__ Xres,
           float* __restrict__ Out) {
  extern __shared__ unsigned short lds[];   // 3 * 12288 elems (A 8192 + B 4096 each)
  const int lane = threadIdx.x & 63, wid = threadIdx.x >> 6;
  const int l15 = lane & 15, lg = lane >> 4;
  const int wr = wid >> 1, wcn = wid & 1;

  // XCD swizzle: bid -> (bx, by), col-major within each XCD's contiguous chunk
  const int bid = blockIdx.x;
  const int cpx = gridDim.x >> 3;            // chunk per XCD (grid % 8 == 0)
  const int lin = (bid & 7) * cpx + (bid >> 3);
  const int bx = lin / GY, by = lin % GY;
  const int am0 = bx * 256, bn0 = by * 128;

  const int srow0 = wid * 16 + (lane >> 2);   // 0..63 staging row (+ j*64)
  const int scb0  = (lane & 3) * 16;          // staging linear col-byte

  f32x4 acc[8][4] = {};
  bf16x8 a[8], b[4];

#define SWZ(row) ((((row) >> 1) & 3) << 4)
#define VMC(N) asm volatile("s_waitcnt vmcnt(" #N ")" ::: "memory")

#define STAGE(s) { \
    const int slot_ = (s) % 3; \
    _Pragma("unroll") \
    for (int j = 0; j < 4; ++j) { \
      const int row_ = j * 64 + srow0; \
      const int cs_ = scb0 ^ SWZ(row_); \
      g2l16(A + (size_t)(am0 + row_) * 1024 + (s) * 32 + (cs_ >> 1), \
            &lds[slot_ * 12288 + (j * 64 + wid * 16) * 32]); \
    } \
    _Pragma("unroll") \
    for (int j = 0; j < 2; ++j) { \
      const int row_ = j * 64 + srow0; \
      const int cs_ = scb0 ^ SWZ(row_); \
      g2l16(Bw + (size_t)(bn0 + row_) * 1024 + (s) * 32 + (cs_ >> 1), \
            &lds[slot_ * 12288 + 8192 + (j * 64 + wid * 16) * 32]); \
    } }

#define LOADF(p) { \
    const unsigned short* As_ = &lds[((p) % 3) * 12288]; \
    const unsigned short* Bs_ = As_ + 8192; \
    _Pragma("unroll") \
    for (int mf = 0; mf < 8; ++mf) { \
      const int row_ = wr * 128 + mf * 16 + l15; \
      a[mf] = *(const bf16x8*)((const char*)As_ + row_ * 64 + ((lg * 16) ^ SWZ(row_))); \
    } \
    _Pragma("unroll") \
    for (int nf = 0; nf < 4; ++nf) { \
      const int row_ = wcn * 64 + nf * 16 + l15; \
      b[nf] = *(const bf16x8*)((const char*)Bs_ + row_ * 64 + ((lg * 16) ^ SWZ(row_))); \
    } }

#define MM() { \
    __builtin_amdgcn_s_setprio(1); \
    _Pragma("unroll") \
    for (int mf = 0; mf < 8; ++mf) \
      _Pragma("unroll") \
      for (int nf = 0; nf < 4; ++nf) \
        acc[mf][nf] = __builtin_amdgcn_mfma_f32_16x16x32_bf16(a[mf], b[nf], acc[mf][nf], 0, 0, 0); \
    __builtin_amdgcn_s_setprio(0); }

  STAGE(0) STAGE(1)
  VMC(6);   // slab0 landed (this wave); slab1 in flight

#pragma unroll 1
  for (int p = 0; p < 32; ++p) {
    __builtin_amdgcn_s_barrier();
    if (p < 30) STAGE(p + 2)
    LOADF(p)
    asm volatile("s_waitcnt lgkmcnt(0)" ::: "memory");
    __builtin_amdgcn_sched_barrier(0);
    MM()
    if (p < 29) { VMC(6); } else { VMC(0); }
  }

  // C frag mapping: col = bn0 + wcn*64 + nf*16 + l15 ; row = am0 + wr*128 + mf*16 + lg*4 + r
  if (EPI == 0) {
#pragma unroll
    for (int nf = 0; nf < 4; ++nf) {
      const int col = bn0 + wcn * 64 + nf * 16 + l15;   // 0..3071
      const int which = col >> 10;                      // 0=Q 1=K 2=V (uniform per block)
      const int e = col & 1023;
      const int hh = e >> 6, dd = e & 63;
      const float bv = bias[col];
#pragma unroll
      for (int mf = 0; mf < 8; ++mf) {
        const int row0 = am0 + wr * 128 + mf * 16 + lg * 4;  // multiple of 4
        const int bb = row0 >> 8;
        const int s0 = row0 & 255;
        if (which == 2) {
          unsigned long long pk = 0;
#pragma unroll
          for (int r = 0; r < 4; ++r)
            pk |= (unsigned long long)f2bf(acc[mf][nf][r] + bv) << (16 * r);
          *(unsigned long long*)&VTo[((size_t)(bb * 16 + hh) * 64 + dd) * 256 + s0] = pk;
        } else if (which == 0) {
          // Q pre-scaled by 1/sqrt(D)=0.125 (exact bf16 exponent shift)
#pragma unroll
          for (int r = 0; r < 4; ++r)
            Qo[((size_t)(bb * 16 + hh) * 256 + s0 + r) * 64 + dd] = f2bf((acc[mf][nf][r] + bv) * 0.125f);
        } else {
#pragma unroll
          for (int r = 0; r < 4; ++r)
            Ko[((size_t)(bb * 16 + hh) * 256 + s0 + r) * 64 + dd] = f2bf(acc[mf][nf][r] + bv);
        }
      }
    }
  } else {
#pragma unroll
    for (int nf = 0; nf < 4; ++nf) {
      const int col = bn0 + wcn * 64 + nf * 16 + l15;
      const float bv = bias[col];
#pragma unroll
      for (int mf = 0; mf < 8; ++mf) {
#pragma unroll
        for (int r = 0; r < 4; ++r) {
          const int row = am0 + wr * 128 + mf * 16 + lg * 4 + r;
          const size_t idx = (size_t)row * 1024 + col;
          Out[idx] = Xres[idx] + acc[mf][nf][r] + bv;
        }
      }
    }
  }
#undef SWZ
#undef VMC
#undef STAGE
#undef LOADF
#undef MM
}

// ---------------------------------------------------------------- fused attention
// (frozen at R9 state: K bulk-staged to LDS w/ granule-XOR swizzle + R7's
// order-independent vmcnt(0) handshake; T13 defer-max; bias bf16; Q pre-scaled;
// (256,2) — 2 blocks/CU is this structure's occupancy ceiling, R8 proved 3 spills.)
__global__ __launch_bounds__(256, 2)
void attn_kernel(const unsigned short* __restrict__ Qg,
                 const unsigned short* __restrict__ Kg,
                 const unsigned short* __restrict__ VTg,
                 const unsigned short* __restrict__ biasbf,
                 unsigned short* __restrict__ ctx) {
  __shared__ unsigned short Ks[256 * 64];   // 32KB swizzled K
  __shared__ unsigned short P[4][64][40];   // per-wave [q][k32], pad 32->40 (20KB)
  const int lane = threadIdx.x & 63, wave = threadIdx.x >> 6;
  const int l15 = lane & 15, lg = lane >> 4;
  const int bh = blockIdx.x;
  const int bb = bh >> 4, hh = bh & 15;
  const size_t base = (size_t)bh * (256 * 64);
  const int q0 = wave * 64;

  // ---- bulk K stage: 2048 granules(16B); issue j covers rows (wave*8+j)*8..+7
#pragma unroll
  for (int j = 0; j < 8; ++j) {
    const int r0 = (wave * 8 + j) * 8;
    const int row = r0 + (lane >> 3);
    const int gsrc = (lane & 7) ^ (row & 7);
    g2l16(&Kg[base + (size_t)row * 64 + gsrc * 8], &Ks[r0 * 64]);
  }
  // Order-independent drain: ALL this wave's vmem done before signaling.
  asm volatile("s_waitcnt vmcnt(0)" ::: "memory");
  __builtin_amdgcn_sched_barrier(0);
  __builtin_amdgcn_s_barrier();                     // all waves' K staged

  // Q fragments (after barrier; pre-scaled by 0.125 in gemm0)
  bf16x8 qfr[4][2];
#pragma unroll
  for (int qi = 0; qi < 4; ++qi)
#pragma unroll
    for (int kc = 0; kc < 2; ++kc)
      qfr[qi][kc] = *(const bf16x8*)&Qg[base + (size_t)(q0 + qi * 16 + l15) * 64 + kc * 32 + lg * 8];

  f32x4 o[4][4] = {};
  float mrow[4], lrow[4];
#pragma unroll
  for (int i = 0; i < 4; ++i) { mrow[i] = -1e30f; lrow[i] = 0.f; }

#pragma unroll 1
  for (int c = 0; c < 8; ++c) {
    const int ck = c * 32;
    // V + bias issues first (global; longest latency to use)
    bf16x8 vb[4];
#pragma unroll
    for (int df = 0; df < 4; ++df)
      vb[df] = *(const bf16x8*)&VTg[base + (size_t)(df * 16 + l15) * 256 + ck + lg * 8];
    ushort4 bbf[2][4];
#pragma unroll
    for (int kr = 0; kr < 2; ++kr)
#pragma unroll
      for (int qi = 0; qi < 4; ++qi)
        bbf[kr][qi] = *(const ushort4*)&biasbf[(q0 + qi * 16 + l15) * 256 + ck + kr * 16 + lg * 4];
    // K fragments from LDS (swizzled granule)
    bf16x8 kf[2][2];
#pragma unroll
    for (int kr = 0; kr < 2; ++kr)
#pragma unroll
      for (int kc = 0; kc < 2; ++kc) {
        const int row = ck + kr * 16 + l15;
        const int g = (kc * 4 + lg) ^ (row & 7);
        kf[kr][kc] = *(const bf16x8*)&Ks[row * 64 + g * 8];
      }
    // S^T chunk [32k x 64q] = mfma(K, Q)
    f32x4 s[2][4] = {};
#pragma unroll
    for (int kr = 0; kr < 2; ++kr)
#pragma unroll
      for (int qi = 0; qi < 4; ++qi)
#pragma unroll
        for (int kc = 0; kc < 2; ++kc)
          s[kr][qi] = __builtin_amdgcn_mfma_f32_16x16x32_bf16(kf[kr][kc], qfr[qi][kc], s[kr][qi], 0, 0, 0);

    // + bias (Q pre-scaled, so no multiply); per-q chunk max
    float cmax[4];
#pragma unroll
    for (int qi = 0; qi < 4; ++qi) cmax[qi] = -1e30f;
#pragma unroll
    for (int kr = 0; kr < 2; ++kr)
#pragma unroll
      for (int qi = 0; qi < 4; ++qi) {
        const unsigned short* bp = (const unsigned short*)&bbf[kr][qi];
#pragma unroll
        for (int r = 0; r < 4; ++r) {
          float v = s[kr][qi][r] + bf2f(bp[r]);
          s[kr][qi][r] = v;
          cmax[qi] = fmaxf(cmax[qi], v);
        }
      }
#pragma unroll
    for (int qi = 0; qi < 4; ++qi) {
      cmax[qi] = fmaxf(cmax[qi], __shfl_xor(cmax[qi], 16, 64));
      cmax[qi] = fmaxf(cmax[qi], __shfl_xor(cmax[qi], 32, 64));
    }
    // T13 defer-max: skip rescale when no q-row grew its max by >8
    int defer = 1;
#pragma unroll
    for (int qi = 0; qi < 4; ++qi) defer &= (cmax[qi] - mrow[qi] <= 8.f);
    const int full = !__all(defer);   // wave-uniform
    float resc[4];
#pragma unroll
    for (int qi = 0; qi < 4; ++qi) {
      if (full) {
        float mn = fmaxf(mrow[qi], cmax[qi]);
        resc[qi] = __expf(mrow[qi] - mn);
        mrow[qi] = mn;
      } else resc[qi] = 1.f;
    }
    float csum[4];
#pragma unroll
    for (int qi = 0; qi < 4; ++qi) csum[qi] = 0.f;
#pragma unroll
    for (int kr = 0; kr < 2; ++kr)
#pragma unroll
      for (int qi = 0; qi < 4; ++qi)
#pragma unroll
        for (int r = 0; r < 4; ++r) {
          float e = __expf(s[kr][qi][r] - mrow[qi]);
          s[kr][qi][r] = e;
          csum[qi] += e;
        }
#pragma unroll
    for (int qi = 0; qi < 4; ++qi) {
      csum[qi] += __shfl_xor(csum[qi], 16, 64);
      csum[qi] += __shfl_xor(csum[qi], 32, 64);
      lrow[qi] = lrow[qi] * resc[qi] + csum[qi];
    }
    // P -> LDS transposed to [q][k] (per-wave private), packed b64 writes
#pragma unroll
    for (int kr = 0; kr < 2; ++kr)
#pragma unroll
      for (int qi = 0; qi < 4; ++qi) {
        unsigned long long pk = 0;
#pragma unroll
        for (int r = 0; r < 4; ++r)
          pk |= (unsigned long long)f2bf(s[kr][qi][r]) << (16 * r);
        *(unsigned long long*)&P[wave][qi * 16 + l15][kr * 16 + lg * 4] = pk;
      }
    asm volatile("s_waitcnt lgkmcnt(0)" ::: "memory");
    // O rescale only on the full path
    if (full) {
#pragma unroll
      for (int qrf = 0; qrf < 4; ++qrf)
#pragma unroll
        for (int r = 0; r < 4; ++r) {
          float f = __shfl(resc[qrf], lg * 4 + r, 64);
#pragma unroll
          for (int df = 0; df < 4; ++df) o[qrf][df][r] *= f;
        }
    }
    // PV: A = P[q][k] from LDS, B = V chunk
    bf16x8 pa[4];
#pragma unroll
    for (int qrf = 0; qrf < 4; ++qrf)
      pa[qrf] = *(const bf16x8*)&P[wave][qrf * 16 + l15][lg * 8];
#pragma unroll
    for (int qrf = 0; qrf < 4; ++qrf)
#pragma unroll
      for (int df = 0; df < 4; ++df)
        o[qrf][df] = __builtin_amdgcn_mfma_f32_16x16x32_bf16(pa[qrf], vb[df], o[qrf][df], 0, 0, 0);
  }

  // normalize and write ctx [B,S,E] bf16
#pragma unroll
  for (int qrf = 0; qrf < 4; ++qrf)
#pragma unroll
    for (int r = 0; r < 4; ++r) {
      float li = __shfl(lrow[qrf], lg * 4 + r, 64);
      float inv = 1.0f / li;
      const int q = q0 + qrf * 16 + lg * 4 + r;
#pragma unroll
      for (int df = 0; df < 4; ++df) {
        const int d = df * 16 + l15;
        ctx[((size_t)(bb * 256 + q) * 16 + hh) * 64 + d] = f2bf(o[qrf][df][r] * inv);
      }
    }
}

// ---------------------------------------------------------------- launch
extern "C" void kernel_launch(void* const* d_in, const int* in_sizes, int n_in,
                              void* d_out, int out_size, void* d_ws, size_t ws_size,
                              hipStream_t stream) {
  const float* x  = (const float*)d_in[0];
  const float* wi = (const float*)d_in[1];
  const float* bi = (const float*)d_in[2];
  const float* wo = (const float*)d_in[3];
  const float* bo = (const float*)d_in[4];
  const float* sb = (const float*)d_in[5];
  float* out = (float*)d_out;

  char* ws = (char*)d_ws;
  // ws layout (bytes): x_bf/ctx 33554432 | w_in 6291456 | w_out 2097152 | Q | K | VT
  unsigned short* xbf  = (unsigned short*)(ws);
  unsigned short* winb = (unsigned short*)(ws + 33554432u);
  unsigned short* wob  = (unsigned short*)(ws + 39845888u);
  unsigned short* Qb   = (unsigned short*)(ws + 41943040u);
  unsigned short* Kb   = (unsigned short*)(ws + 75497472u);
  unsigned short* VTb  = (unsigned short*)(ws + 109051904u);
  unsigned short* ctx  = xbf;   // x_bf dead after QKV GEMM; reuse for ctx
  unsigned short* sbbf = winb;  // w_in dead after gemm0; bias-bf16 cvt'd there

  // 72KB dynamic LDS needs the attribute raised past the 64KB default
  (void)hipFuncSetAttribute(reinterpret_cast<const void*>(gemm4<0, 24>),
                            hipFuncAttributeMaxDynamicSharedMemorySize, 73728);
  (void)hipFuncSetAttribute(reinterpret_cast<const void*>(gemm4<1, 8>),
                            hipFuncAttributeMaxDynamicSharedMemorySize, 73728);

  cvt_kernel<<<16384, 256, 0, stream>>>(x, xbf, 16777216);
  cvt_kernel<<<3072, 256, 0, stream>>>(wi, winb, 3145728);
  cvt_kernel<<<1024, 256, 0, stream>>>(wo, wob, 1048576);

  // QKV: M=16384 N=3072 K=1024; 1D grid 64x24=1536 (div by 8), XCD-swizzled
  gemm4<0, 24><<<1536, 256, 73728, stream>>>(xbf, winb, bi, Qb, Kb, VTb, nullptr, nullptr);

  // bias -> bf16 into the now-dead w_in region (64 blocks, 65536 elems)
  cvt_kernel<<<64, 256, 0, stream>>>(sb, sbbf, 65536);

  // attention: one block per (b,h)
  attn_kernel<<<1024, 256, 0, stream>>>(Qb, Kb, VTb, sbbf, ctx);

  // out-proj + residual: M=16384 N=1024 K=1024; 1D grid 64x8=512, XCD-swizzled
  gemm4<1, 8><<<512, 256, 73728, stream>>>(ctx, wob, bo, nullptr, nullptr, nullptr, x, out);
}

// Round 12
// 285.270 us; speedup vs baseline: 1.0127x; 1.0127x over previous
//
#include <hip/hip_runtime.h>
#include <hip/hip_bf16.h>
#include <stdint.h>

// SpatialMHA: B=64 S=256 E=1024 H=16 D=64
// qkv = x @ Win^T + bin ; attn with additive spatial bias ; out = x + ctx @ Wout^T + bout

typedef __attribute__((ext_vector_type(8))) __bf16 bf16x8;
typedef __attribute__((ext_vector_type(4))) float f32x4;

#define DEVI static __device__ __forceinline__

DEVI unsigned short f2bf(float f) {           // fp32 -> bf16 round-to-nearest-even
  union { float f; unsigned u; } x; x.f = f;
  unsigned r = x.u + 0x7fffu + ((x.u >> 16) & 1u);
  return (unsigned short)(r >> 16);
}

DEVI float bf2f(unsigned short h) {
  union { unsigned u; float f; } x; x.u = (unsigned)h << 16; return x.f;
}

typedef unsigned int __attribute__((address_space(1))) u32_g;
typedef unsigned int __attribute__((address_space(3))) u32_l;

DEVI void g2l16(const unsigned short* g, unsigned short* l) {
  // async global->LDS, 16B per lane; LDS dest = wave-uniform base + lane*16
  __builtin_amdgcn_global_load_lds((const u32_g*)g, (u32_l*)l, 16, 0, 0);
}

// ---------------------------------------------------------------- fp32->bf16
__global__ __launch_bounds__(256) void cvt_kernel(const float* __restrict__ s,
                                                  unsigned short* __restrict__ d, int n) {
  int i = (blockIdx.x * 256 + threadIdx.x) * 4;
  if (i >= n) return;
  float4 v = *(const float4*)(s + i);
  ushort4 o;
  o.x = f2bf(v.x); o.y = f2bf(v.y); o.z = f2bf(v.z); o.w = f2bf(v.w);
  *(ushort4*)(d + i) = o;
}

// ---------------------------------------------------------------- 256x256 GEMM, faithful 8-phase
// R11: exact m201 two-barrier 8-phase schedule (previous ports deviated: 1 barrier/
// phase + vmcnt(2) over-drain). 8 waves (2M x 4N), per-wave 128x64 C (acc 128 AGPR).
// K=1024 = 16 K-tiles of BK=64, iters of 2 K-tiles (k0,k1). LDS 128KB = 2 bufs x
// {A,B} x 2 halves (128 rows x 64 cols, 16KB each). Phase = {ds_read quadrant frags
// || stage} -> s_barrier -> lgkmcnt(0) -> setprio(1) 16 MFMA setprio(0) -> s_barrier.
// vmcnt(6) ONLY at p4/p8 (3 half-tile stages = 6 loads in flight, never drained to 0).
// Quadrants per K-tile: p1 Q1=aLo*b0, p2 Q2=aLo*b1, p3 Q3=aHi*b1, p4 Q4=aHi*b0.
// Region read windows: A halves read p1&p3, B halves p1&p2 (different waves read
// different halves; all 4 halves of a K-tile are consumed from its first phase).
// Stage plan (iter i): p1:Ahi(k1) | p3:Blo(k0+2) | p4:Bhi(k0+2)+Alo(k0+2),vmcnt(6)
// | p5:Ahi(k0+2) | p7:Blo(k1+2) | p8:Bhi(k1+2)+Alo(k1+2),vmcnt(6).
//  - overwrite safety: each stage >=1 barrier after the overwritten region's last
//    ds_read drained (reader lgkm precedes its phase's MFMA & end barrier).
//  - availability: p4's vmcnt(6) => stages <= p1 landed => k1 complete before p5;
//    p8's vmcnt(6) => stages <= p5 landed => k0+2 complete before next-iter p1.
// Swizzle for 128B rows: granule(16B) ^= (row>>1)&7 on stage source AND ds_read =>
// every frag-read spreads 8 lanes/granule = 2 lanes/bank (free, m136). Prologue:
// kt0 x4 halves + kt1 {Blo,Bhi,Alo}; vmcnt(6) => kt0 landed. Tail iter7: only
// Ahi(15)@p1, vmcnt(0)@p4.
template <int EPI>
__global__ __launch_bounds__(512, 1)
void gemm8p(const unsigned short* __restrict__ A,
            const unsigned short* __restrict__ Bw,
            const float* __restrict__ bias,
            unsigned short* __restrict__ Qo,
            unsigned short* __restrict__ Ko,
            unsigned short* __restrict__ VTo,
            const float* __restrict__ Xres,
            float* __restrict__ Out) {
  extern __shared__ unsigned short lds[];   // 65536 elems = 128KB
  const int lane = threadIdx.x & 63, wid = threadIdx.x >> 6;
  const int l15 = lane & 15, lg = lane >> 4;
  const int wr = wid >> 2, wcn = wid & 3;
  const int am0 = blockIdx.x * 256, bn0 = blockIdx.y * 256;

  const int sr = wid * 8 + (lane >> 3);   // staging row within 64-row group
  const int sg = lane & 7;                // staging linear granule

  f32x4 acc[8][4] = {};
  bf16x8 a[4][2], b0[2][2], b1[2][2];

#define VMC(N) asm volatile("s_waitcnt vmcnt(" #N ")" ::: "memory")
#define LGKM() asm volatile("s_waitcnt lgkmcnt(0)" ::: "memory")
#define BARR() __builtin_amdgcn_s_barrier()
#define SW(r) (((r) >> 1) & 7)

  // stage one half-tile (128 rows x 64 cols = 16KB) of operand OP, K-tile KT
#define STG(OP, KT, HALF) { \
    _Pragma("unroll") \
    for (int j = 0; j < 2; ++j) { \
      const int rin_ = j * 64 + sr; \
      const int gs_ = sg ^ SW(rin_); \
      const unsigned short* src_ = ((OP) ? Bw + (size_t)(bn0 + (HALF) * 128 + rin_) * 1024 \
                                         : A  + (size_t)(am0 + (HALF) * 128 + rin_) * 1024) \
                                   + (KT) * 64 + gs_ * 8; \
      g2l16(src_, &lds[((KT) & 1) * 32768 + (OP) * 16384 + (HALF) * 8192 + (j * 64 + wid * 8) * 64]); \
    } }

#define RDA(KT, HA) { \
    const unsigned short* r_ = &lds[((KT) & 1) * 32768 + wr * 8192]; \
    _Pragma("unroll") \
    for (int mfi = 0; mfi < 4; ++mfi) { \
      const int rin_ = (HA) * 64 + mfi * 16 + l15; \
      _Pragma("unroll") \
      for (int kk = 0; kk < 2; ++kk) \
        a[mfi][kk] = *(const bf16x8*)&r_[rin_ * 64 + ((kk * 4 + lg) ^ SW(rin_)) * 8]; \
    } }

#define RDB(BF, KT, HB) { \
    const unsigned short* r_ = &lds[((KT) & 1) * 32768 + 16384 + (wcn >> 1) * 8192]; \
    _Pragma("unroll") \
    for (int nfi = 0; nfi < 2; ++nfi) { \
      const int rin_ = (wcn & 1) * 64 + (HB) * 32 + nfi * 16 + l15; \
      _Pragma("unroll") \
      for (int kk = 0; kk < 2; ++kk) \
        BF[nfi][kk] = *(const bf16x8*)&r_[rin_ * 64 + ((kk * 4 + lg) ^ SW(rin_)) * 8]; \
    } }

#define MM(BF, HA, HB) { \
    __builtin_amdgcn_s_setprio(1); \
    _Pragma("unroll") \
    for (int mfi = 0; mfi < 4; ++mfi) \
      _Pragma("unroll") \
      for (int nfi = 0; nfi < 2; ++nfi) \
        _Pragma("unroll") \
        for (int kk = 0; kk < 2; ++kk) \
          acc[(HA) * 4 + mfi][(HB) * 2 + nfi] = __builtin_amdgcn_mfma_f32_16x16x32_bf16( \
              a[mfi][kk], BF[nfi][kk], acc[(HA) * 4 + mfi][(HB) * 2 + nfi], 0, 0, 0); \
    __builtin_amdgcn_s_setprio(0); }

  // prologue: kt0 {Alo,Ahi,Blo,Bhi} then kt1 {Blo,Bhi,Alo}; vmcnt(6) -> kt0 landed
  STG(0, 0, 0) STG(0, 0, 1) STG(1, 0, 0) STG(1, 0, 1)
  STG(1, 1, 0) STG(1, 1, 1) STG(0, 1, 0)
  VMC(6); BARR();

#pragma unroll 1
  for (int i = 0; i < 7; ++i) {
    const int k0 = 2 * i, k1 = 2 * i + 1;
    RDA(k0, 0) RDB(b0, k0, 0) STG(0, k1, 1)              BARR(); LGKM(); MM(b0, 0, 0) BARR();  // p1
    RDB(b1, k0, 1)                                       BARR(); LGKM(); MM(b1, 0, 1) BARR();  // p2
    RDA(k0, 1)                STG(1, k0 + 2, 0)          BARR(); LGKM(); MM(b1, 1, 1) BARR();  // p3
    STG(1, k0 + 2, 1) STG(0, k0 + 2, 0)          VMC(6); BARR();         MM(b0, 1, 0) BARR();  // p4
    RDA(k1, 0) RDB(b0, k1, 0) STG(0, k0 + 2, 1)          BARR(); LGKM(); MM(b0, 0, 0) BARR();  // p5
    RDB(b1, k1, 1)                                       BARR(); LGKM(); MM(b1, 0, 1) BARR();  // p6
    RDA(k1, 1)                STG(1, k1 + 2, 0)          BARR(); LGKM(); MM(b1, 1, 1) BARR();  // p7
    STG(1, k1 + 2, 1) STG(0, k1 + 2, 0)          VMC(6); BARR();         MM(b0, 1, 0) BARR();  // p8
  }
  // tail iter 7: kts 14,15; only Ahi(15) left to stage
  RDA(14, 0) RDB(b0, 14, 0) STG(0, 15, 1)                BARR(); LGKM(); MM(b0, 0, 0) BARR();
  RDB(b1, 14, 1)                                         BARR(); LGKM(); MM(b1, 0, 1) BARR();
  RDA(14, 1)                                             BARR(); LGKM(); MM(b1, 1, 1) BARR();
                                               VMC(0);   BARR();         MM(b0, 1, 0) BARR();
  RDA(15, 0) RDB(b0, 15, 0)                              BARR(); LGKM(); MM(b0, 0, 0) BARR();
  RDB(b1, 15, 1)                                         BARR(); LGKM(); MM(b1, 0, 1) BARR();
  RDA(15, 1)                                             BARR(); LGKM(); MM(b1, 1, 1) BARR();
                                                                         MM(b0, 1, 0)

  // C frag mapping: col = bn0 + wcn*64 + nf*16 + l15 ; row = am0 + wr*128 + mf*16 + lg*4 + r
  if (EPI == 0) {
#pragma unroll
    for (int nf = 0; nf < 4; ++nf) {
      const int col = bn0 + wcn * 64 + nf * 16 + l15;   // 0..3071
      const int which = col >> 10;                      // 0=Q 1=K 2=V (uniform per block)
      const int e = col & 1023;
      const int hh = e >> 6, dd = e & 63;
      const float bv = bias[col];
#pragma unroll
      for (int mf = 0; mf < 8; ++mf) {
        const int row0 = am0 + wr * 128 + mf * 16 + lg * 4;  // multiple of 4
        const int bb = row0 >> 8;
        const int s0 = row0 & 255;
        if (which == 2) {
          unsigned long long pk = 0;
#pragma unroll
          for (int r = 0; r < 4; ++r)
            pk |= (unsigned long long)f2bf(acc[mf][nf][r] + bv) << (16 * r);
          *(unsigned long long*)&VTo[((size_t)(bb * 16 + hh) * 64 + dd) * 256 + s0] = pk;
        } else if (which == 0) {
          // Q pre-scaled by 1/sqrt(D)=0.125 (exact bf16 exponent shift)
#pragma unroll
          for (int r = 0; r < 4; ++r)
            Qo[((size_t)(bb * 16 + hh) * 256 + s0 + r) * 64 + dd] = f2bf((acc[mf][nf][r] + bv) * 0.125f);
        } else {
#pragma unroll
          for (int r = 0; r < 4; ++r)
            Ko[((size_t)(bb * 16 + hh) * 256 + s0 + r) * 64 + dd] = f2bf(acc[mf][nf][r] + bv);
        }
      }
    }
  } else {
#pragma unroll
    for (int nf = 0; nf < 4; ++nf) {
      const int col = bn0 + wcn * 64 + nf * 16 + l15;
      const float bv = bias[col];
#pragma unroll
      for (int mf = 0; mf < 8; ++mf) {
#pragma unroll
        for (int r = 0; r < 4; ++r) {
          const int row = am0 + wr * 128 + mf * 16 + lg * 4 + r;
          const size_t idx = (size_t)row * 1024 + col;
          Out[idx] = Xres[idx] + acc[mf][nf][r] + bv;
        }
      }
    }
  }
#undef VMC
#undef LGKM
#undef BARR
#undef SW
#undef STG
#undef RDA
#undef RDB
#undef MM
}

// ---------------------------------------------------------------- fused attention
// (frozen at R9 state: K bulk-staged to LDS w/ granule-XOR swizzle + R7's
// order-independent vmcnt(0) handshake; T13 defer-max; bias bf16; Q pre-scaled;
// (256,2) — 2 blocks/CU is this structure's occupancy ceiling, R8 proved 3 spills.)
__global__ __launch_bounds__(256, 2)
void attn_kernel(const unsigned short* __restrict__ Qg,
                 const unsigned short* __restrict__ Kg,
                 const unsigned short* __restrict__ VTg,
                 const unsigned short* __restrict__ biasbf,
                 unsigned short* __restrict__ ctx) {
  __shared__ unsigned short Ks[256 * 64];   // 32KB swizzled K
  __shared__ unsigned short P[4][64][40];   // per-wave [q][k32], pad 32->40 (20KB)
  const int lane = threadIdx.x & 63, wave = threadIdx.x >> 6;
  const int l15 = lane & 15, lg = lane >> 4;
  const int bh = blockIdx.x;
  const int bb = bh >> 4, hh = bh & 15;
  const size_t base = (size_t)bh * (256 * 64);
  const int q0 = wave * 64;

  // ---- bulk K stage: 2048 granules(16B); issue j covers rows (wave*8+j)*8..+7
#pragma unroll
  for (int j = 0; j < 8; ++j) {
    const int r0 = (wave * 8 + j) * 8;
    const int row = r0 + (lane >> 3);
    const int gsrc = (lane & 7) ^ (row & 7);
    g2l16(&Kg[base + (size_t)row * 64 + gsrc * 8], &Ks[r0 * 64]);
  }
  // Order-independent drain: ALL this wave's vmem done before signaling.
  asm volatile("s_waitcnt vmcnt(0)" ::: "memory");
  __builtin_amdgcn_sched_barrier(0);
  __builtin_amdgcn_s_barrier();                     // all waves' K staged

  // Q fragments (after barrier; pre-scaled by 0.125 in gemm0)
  bf16x8 qfr[4][2];
#pragma unroll
  for (int qi = 0; qi < 4; ++qi)
#pragma unroll
    for (int kc = 0; kc < 2; ++kc)
      qfr[qi][kc] = *(const bf16x8*)&Qg[base + (size_t)(q0 + qi * 16 + l15) * 64 + kc * 32 + lg * 8];

  f32x4 o[4][4] = {};
  float mrow[4], lrow[4];
#pragma unroll
  for (int i = 0; i < 4; ++i) { mrow[i] = -1e30f; lrow[i] = 0.f; }

#pragma unroll 1
  for (int c = 0; c < 8; ++c) {
    const int ck = c * 32;
    // V + bias issues first (global; longest latency to use)
    bf16x8 vb[4];
#pragma unroll
    for (int df = 0; df < 4; ++df)
      vb[df] = *(const bf16x8*)&VTg[base + (size_t)(df * 16 + l15) * 256 + ck + lg * 8];
    ushort4 bbf[2][4];
#pragma unroll
    for (int kr = 0; kr < 2; ++kr)
#pragma unroll
      for (int qi = 0; qi < 4; ++qi)
        bbf[kr][qi] = *(const ushort4*)&biasbf[(q0 + qi * 16 + l15) * 256 + ck + kr * 16 + lg * 4];
    // K fragments from LDS (swizzled granule)
    bf16x8 kf[2][2];
#pragma unroll
    for (int kr = 0; kr < 2; ++kr)
#pragma unroll
      for (int kc = 0; kc < 2; ++kc) {
        const int row = ck + kr * 16 + l15;
        const int g = (kc * 4 + lg) ^ (row & 7);
        kf[kr][kc] = *(const bf16x8*)&Ks[row * 64 + g * 8];
      }
    // S^T chunk [32k x 64q] = mfma(K, Q)
    f32x4 s[2][4] = {};
#pragma unroll
    for (int kr = 0; kr < 2; ++kr)
#pragma unroll
      for (int qi = 0; qi < 4; ++qi)
#pragma unroll
        for (int kc = 0; kc < 2; ++kc)
          s[kr][qi] = __builtin_amdgcn_mfma_f32_16x16x32_bf16(kf[kr][kc], qfr[qi][kc], s[kr][qi], 0, 0, 0);

    // + bias (Q pre-scaled, so no multiply); per-q chunk max
    float cmax[4];
#pragma unroll
    for (int qi = 0; qi < 4; ++qi) cmax[qi] = -1e30f;
#pragma unroll
    for (int kr = 0; kr < 2; ++kr)
#pragma unroll
      for (int qi = 0; qi < 4; ++qi) {
        const unsigned short* bp = (const unsigned short*)&bbf[kr][qi];
#pragma unroll
        for (int r = 0; r < 4; ++r) {
          float v = s[kr][qi][r] + bf2f(bp[r]);
          s[kr][qi][r] = v;
          cmax[qi] = fmaxf(cmax[qi], v);
        }
      }
#pragma unroll
    for (int qi = 0; qi < 4; ++qi) {
      cmax[qi] = fmaxf(cmax[qi], __shfl_xor(cmax[qi], 16, 64));
      cmax[qi] = fmaxf(cmax[qi], __shfl_xor(cmax[qi], 32, 64));
    }
    // T13 defer-max: skip rescale when no q-row grew its max by >8
    int defer = 1;
#pragma unroll
    for (int qi = 0; qi < 4; ++qi) defer &= (cmax[qi] - mrow[qi] <= 8.f);
    const int full = !__all(defer);   // wave-uniform
    float resc[4];
#pragma unroll
    for (int qi = 0; qi < 4; ++qi) {
      if (full) {
        float mn = fmaxf(mrow[qi], cmax[qi]);
        resc[qi] = __expf(mrow[qi] - mn);
        mrow[qi] = mn;
      } else resc[qi] = 1.f;
    }
    float csum[4];
#pragma unroll
    for (int qi = 0; qi < 4; ++qi) csum[qi] = 0.f;
#pragma unroll
    for (int kr = 0; kr < 2; ++kr)
#pragma unroll
      for (int qi = 0; qi < 4; ++qi)
#pragma unroll
        for (int r = 0; r < 4; ++r) {
          float e = __expf(s[kr][qi][r] - mrow[qi]);
          s[kr][qi][r] = e;
          csum[qi] += e;
        }
#pragma unroll
    for (int qi = 0; qi < 4; ++qi) {
      csum[qi] += __shfl_xor(csum[qi], 16, 64);
      csum[qi] += __shfl_xor(csum[qi], 32, 64);
      lrow[qi] = lrow[qi] * resc[qi] + csum[qi];
    }
    // P -> LDS transposed to [q][k] (per-wave private), packed b64 writes
#pragma unroll
    for (int kr = 0; kr < 2; ++kr)
#pragma unroll
      for (int qi = 0; qi < 4; ++qi) {
        unsigned long long pk = 0;
#pragma unroll
        for (int r = 0; r < 4; ++r)
          pk |= (unsigned long long)f2bf(s[kr][qi][r]) << (16 * r);
        *(unsigned long long*)&P[wave][qi * 16 + l15][kr * 16 + lg * 4] = pk;
      }
    asm volatile("s_waitcnt lgkmcnt(0)" ::: "memory");
    // O rescale only on the full path
    if (full) {
#pragma unroll
      for (int qrf = 0; qrf < 4; ++qrf)
#pragma unroll
        for (int r = 0; r < 4; ++r) {
          float f = __shfl(resc[qrf], lg * 4 + r, 64);
#pragma unroll
          for (int df = 0; df < 4; ++df) o[qrf][df][r] *= f;
        }
    }
    // PV: A = P[q][k] from LDS, B = V chunk
    bf16x8 pa[4];
#pragma unroll
    for (int qrf = 0; qrf < 4; ++qrf)
      pa[qrf] = *(const bf16x8*)&P[wave][qrf * 16 + l15][lg * 8];
#pragma unroll
    for (int qrf = 0; qrf < 4; ++qrf)
#pragma unroll
      for (int df = 0; df < 4; ++df)
        o[qrf][df] = __builtin_amdgcn_mfma_f32_16x16x32_bf16(pa[qrf], vb[df], o[qrf][df], 0, 0, 0);
  }

  // normalize and write ctx [B,S,E] bf16
#pragma unroll
  for (int qrf = 0; qrf < 4; ++qrf)
#pragma unroll
    for (int r = 0; r < 4; ++r) {
      float li = __shfl(lrow[qrf], lg * 4 + r, 64);
      float inv = 1.0f / li;
      const int q = q0 + qrf * 16 + lg * 4 + r;
#pragma unroll
      for (int df = 0; df < 4; ++df) {
        const int d = df * 16 + l15;
        ctx[((size_t)(bb * 256 + q) * 16 + hh) * 64 + d] = f2bf(o[qrf][df][r] * inv);
      }
    }
}

// ---------------------------------------------------------------- launch
extern "C" void kernel_launch(void* const* d_in, const int* in_sizes, int n_in,
                              void* d_out, int out_size, void* d_ws, size_t ws_size,
                              hipStream_t stream) {
  const float* x  = (const float*)d_in[0];
  const float* wi = (const float*)d_in[1];
  const float* bi = (const float*)d_in[2];
  const float* wo = (const float*)d_in[3];
  const float* bo = (const float*)d_in[4];
  const float* sb = (const float*)d_in[5];
  float* out = (float*)d_out;

  char* ws = (char*)d_ws;
  // ws layout (bytes): x_bf/ctx 33554432 | w_in 6291456 | w_out 2097152 | Q | K | VT
  unsigned short* xbf  = (unsigned short*)(ws);
  unsigned short* winb = (unsigned short*)(ws + 33554432u);
  unsigned short* wob  = (unsigned short*)(ws + 39845888u);
  unsigned short* Qb   = (unsigned short*)(ws + 41943040u);
  unsigned short* Kb   = (unsigned short*)(ws + 75497472u);
  unsigned short* VTb  = (unsigned short*)(ws + 109051904u);
  unsigned short* ctx  = xbf;   // x_bf dead after QKV GEMM; reuse for ctx
  unsigned short* sbbf = winb;  // w_in dead after gemm0; bias-bf16 cvt'd there

  // 128KB dynamic LDS needs the attribute raised past the 64KB default
  (void)hipFuncSetAttribute(reinterpret_cast<const void*>(gemm8p<0>),
                            hipFuncAttributeMaxDynamicSharedMemorySize, 131072);
  (void)hipFuncSetAttribute(reinterpret_cast<const void*>(gemm8p<1>),
                            hipFuncAttributeMaxDynamicSharedMemorySize, 131072);

  cvt_kernel<<<16384, 256, 0, stream>>>(x, xbf, 16777216);
  cvt_kernel<<<3072, 256, 0, stream>>>(wi, winb, 3145728);
  cvt_kernel<<<1024, 256, 0, stream>>>(wo, wob, 1048576);

  // QKV: M=16384 N=3072 K=1024  (Q pre-scaled by 0.125 in epilogue)
  gemm8p<0><<<dim3(64, 12), 512, 131072, stream>>>(xbf, winb, bi, Qb, Kb, VTb, nullptr, nullptr);

  // bias -> bf16 into the now-dead w_in region (64 blocks, 65536 elems)
  cvt_kernel<<<64, 256, 0, stream>>>(sb, sbbf, 65536);

  // attention: one block per (b,h)
  attn_kernel<<<1024, 256, 0, stream>>>(Qb, Kb, VTb, sbbf, ctx);

  // out-proj + residual: M=16384 N=1024 K=1024
  gemm8p<1><<<dim3(64, 4), 512, 131072, stream>>>(ctx, wob, bo, nullptr, nullptr, nullptr, x, out);
}

// Round 13
// 269.451 us; speedup vs baseline: 1.0721x; 1.0587x over previous
//
#include <hip/hip_runtime.h>
#include <hip/hip_bf16.h>
#include <stdint.h>

// SpatialMHA: B=64 S=256 E=1024 H=16 D=64
// qkv = x @ Win^T + bin ; attn with additive spatial bias ; out = x + ctx @ Wout^T + bout

typedef __attribute__((ext_vector_type(8))) __bf16 bf16x8;
typedef __attribute__((ext_vector_type(4))) float f32x4;

#define DEVI static __device__ __forceinline__

DEVI unsigned short f2bf(float f) {           // fp32 -> bf16 round-to-nearest-even
  union { float f; unsigned u; } x; x.f = f;
  unsigned r = x.u + 0x7fffu + ((x.u >> 16) & 1u);
  return (unsigned short)(r >> 16);
}

DEVI float bf2f(unsigned short h) {
  union { unsigned u; float f; } x; x.u = (unsigned)h << 16; return x.f;
}

typedef unsigned int __attribute__((address_space(1))) u32_g;
typedef unsigned int __attribute__((address_space(3))) u32_l;

DEVI void g2l16(const unsigned short* g, unsigned short* l) {
  // async global->LDS, 16B per lane; LDS dest = wave-uniform base + lane*16
  __builtin_amdgcn_global_load_lds((const u32_g*)g, (u32_l*)l, 16, 0, 0);
}

// ---------------------------------------------------------------- fp32->bf16
__global__ __launch_bounds__(256) void cvt_kernel(const float* __restrict__ s,
                                                  unsigned short* __restrict__ d, int n) {
  int i = (blockIdx.x * 256 + threadIdx.x) * 4;
  if (i >= n) return;
  float4 v = *(const float4*)(s + i);
  ushort4 o;
  o.x = f2bf(v.x); o.y = f2bf(v.y); o.z = f2bf(v.z); o.w = f2bf(v.w);
  *(ushort4*)(d + i) = o;
}

// ---------------------------------------------------------------- 128x128 GEMM (R0 structure + swizzle)
// R12: the R0/m97 structure (128^2 tile, 4 waves 2x2, BK=64, 32KB static LDS,
// __syncthreads per K-step, global_load_lds width 16) was the only config this
// session with real TLP (occupancy 40%, 4-5 blocks/CU) — it hit 146us WITH a
// 3.8e7-count 16-way LDS bank conflict on its dominant read phase (m136: ~5.7x).
// Every later schedule fixed conflicts but traded occupancy to 8 waves/CU and
// plateaued at 140-150us. This round: R0 verbatim + granule XOR swizzle only.
//   stage: lane L of seg writes LDS row seg*8+(L>>3), granule L&7; source granule
//          (L&7)^(L>>3)  => LDS[row][x] holds global granule x^(row&7).
//   read:  global granule g=kk*4+lg at LDS granule g^(row&7) => 16 lanes hit
//          8 granule-cols x 2 rows = 2 lanes/bank = conflict-free (m136).
// EPI==0 epilogue pre-scales Q by 0.125 (exact bf16 exponent shift).
template <int EPI>
__global__ __launch_bounds__(256, 2)
void gemm_bt(const unsigned short* __restrict__ A,
             const unsigned short* __restrict__ Bw,
             const float* __restrict__ bias,
             unsigned short* __restrict__ Qo,
             unsigned short* __restrict__ Ko,
             unsigned short* __restrict__ VTo,
             const float* __restrict__ Xres,
             float* __restrict__ Out) {
  __shared__ unsigned short As[8192];   // [128][64] bf16, 16KB, granule-swizzled
  __shared__ unsigned short Bs[8192];
  const int lane = threadIdx.x & 63, wave = threadIdx.x >> 6;
  const int l15 = lane & 15, lg = lane >> 4;
  const int wr = wave >> 1, wc = wave & 1;
  const int am0 = blockIdx.x * 128, bn0 = blockIdx.y * 128;

  const int srow8 = lane >> 3;                    // row within 8-row seg
  const int sgsrc = (lane & 7) ^ srow8;           // swizzled source granule

  f32x4 acc[4][4] = {};

  for (int kt = 0; kt < 16; ++kt) {
    const int k0 = kt * 64;
#pragma unroll
    for (int i = 0; i < 4; ++i) {
      const int seg = wave * 4 + i;               // 0..15
      const int row = seg * 8 + srow8;            // 0..127
      g2l16(A  + (size_t)(am0 + row) * 1024 + k0 + sgsrc * 8, &As[seg * 512]);
      g2l16(Bw + (size_t)(bn0 + row) * 1024 + k0 + sgsrc * 8, &Bs[seg * 512]);
    }
    __syncthreads();   // drains vmcnt(0) for global_load_lds
#pragma unroll
    for (int kk = 0; kk < 2; ++kk) {
      bf16x8 a[4], b[4];
#pragma unroll
      for (int mf = 0; mf < 4; ++mf) {
        const int row_ = wr * 64 + mf * 16 + l15;
        a[mf] = *(const bf16x8*)((const char*)As + row_ * 128 + (((kk * 4 + lg) ^ (row_ & 7)) << 4));
      }
#pragma unroll
      for (int nf = 0; nf < 4; ++nf) {
        const int row_ = wc * 64 + nf * 16 + l15;
        b[nf] = *(const bf16x8*)((const char*)Bs + row_ * 128 + (((kk * 4 + lg) ^ (row_ & 7)) << 4));
      }
#pragma unroll
      for (int mf = 0; mf < 4; ++mf)
#pragma unroll
        for (int nf = 0; nf < 4; ++nf)
          acc[mf][nf] = __builtin_amdgcn_mfma_f32_16x16x32_bf16(a[mf], b[nf], acc[mf][nf], 0, 0, 0);
    }
    __syncthreads();
  }

  // C frag mapping: col = bn0 + wc*64 + nf*16 + l15 ; row = am0 + wr*64 + mf*16 + lg*4 + r
  if (EPI == 0) {
#pragma unroll
    for (int nf = 0; nf < 4; ++nf) {
      const int col = bn0 + wc * 64 + nf * 16 + l15;   // 0..3071
      const int which = col >> 10;                     // 0=Q 1=K 2=V (uniform per block)
      const int e = col & 1023;
      const int hh = e >> 6, dd = e & 63;
      const float bv = bias[col];
#pragma unroll
      for (int mf = 0; mf < 4; ++mf) {
        const int row0 = am0 + wr * 64 + mf * 16 + lg * 4;  // multiple of 4
        const int bb = row0 >> 8;
        const int s0 = row0 & 255;
        if (which == 2) {
          unsigned long long pk = 0;
#pragma unroll
          for (int r = 0; r < 4; ++r)
            pk |= (unsigned long long)f2bf(acc[mf][nf][r] + bv) << (16 * r);
          *(unsigned long long*)&VTo[((size_t)(bb * 16 + hh) * 64 + dd) * 256 + s0] = pk;
        } else if (which == 0) {
          // Q pre-scaled by 1/sqrt(D)=0.125 (exact bf16 exponent shift)
#pragma unroll
          for (int r = 0; r < 4; ++r)
            Qo[((size_t)(bb * 16 + hh) * 256 + s0 + r) * 64 + dd] = f2bf((acc[mf][nf][r] + bv) * 0.125f);
        } else {
#pragma unroll
          for (int r = 0; r < 4; ++r)
            Ko[((size_t)(bb * 16 + hh) * 256 + s0 + r) * 64 + dd] = f2bf(acc[mf][nf][r] + bv);
        }
      }
    }
  } else {
#pragma unroll
    for (int nf = 0; nf < 4; ++nf) {
      const int col = bn0 + wc * 64 + nf * 16 + l15;
      const float bv = bias[col];
#pragma unroll
      for (int mf = 0; mf < 4; ++mf) {
#pragma unroll
        for (int r = 0; r < 4; ++r) {
          const int row = am0 + wr * 64 + mf * 16 + lg * 4 + r;
          const size_t idx = (size_t)row * 1024 + col;
          Out[idx] = Xres[idx] + acc[mf][nf][r] + bv;
        }
      }
    }
  }
}

// ---------------------------------------------------------------- fused attention
// (frozen at R9 state: K bulk-staged to LDS w/ granule-XOR swizzle + R7's
// order-independent vmcnt(0) handshake; T13 defer-max; bias bf16; Q pre-scaled;
// (256,2) — 2 blocks/CU is this structure's occupancy ceiling, R8 proved 3 spills.)
__global__ __launch_bounds__(256, 2)
void attn_kernel(const unsigned short* __restrict__ Qg,
                 const unsigned short* __restrict__ Kg,
                 const unsigned short* __restrict__ VTg,
                 const unsigned short* __restrict__ biasbf,
                 unsigned short* __restrict__ ctx) {
  __shared__ unsigned short Ks[256 * 64];   // 32KB swizzled K
  __shared__ unsigned short P[4][64][40];   // per-wave [q][k32], pad 32->40 (20KB)
  const int lane = threadIdx.x & 63, wave = threadIdx.x >> 6;
  const int l15 = lane & 15, lg = lane >> 4;
  const int bh = blockIdx.x;
  const int bb = bh >> 4, hh = bh & 15;
  const size_t base = (size_t)bh * (256 * 64);
  const int q0 = wave * 64;

  // ---- bulk K stage: 2048 granules(16B); issue j covers rows (wave*8+j)*8..+7
#pragma unroll
  for (int j = 0; j < 8; ++j) {
    const int r0 = (wave * 8 + j) * 8;
    const int row = r0 + (lane >> 3);
    const int gsrc = (lane & 7) ^ (row & 7);
    g2l16(&Kg[base + (size_t)row * 64 + gsrc * 8], &Ks[r0 * 64]);
  }
  // Order-independent drain: ALL this wave's vmem done before signaling.
  asm volatile("s_waitcnt vmcnt(0)" ::: "memory");
  __builtin_amdgcn_sched_barrier(0);
  __builtin_amdgcn_s_barrier();                     // all waves' K staged

  // Q fragments (after barrier; pre-scaled by 0.125 in gemm0)
  bf16x8 qfr[4][2];
#pragma unroll
  for (int qi = 0; qi < 4; ++qi)
#pragma unroll
    for (int kc = 0; kc < 2; ++kc)
      qfr[qi][kc] = *(const bf16x8*)&Qg[base + (size_t)(q0 + qi * 16 + l15) * 64 + kc * 32 + lg * 8];

  f32x4 o[4][4] = {};
  float mrow[4], lrow[4];
#pragma unroll
  for (int i = 0; i < 4; ++i) { mrow[i] = -1e30f; lrow[i] = 0.f; }

#pragma unroll 1
  for (int c = 0; c < 8; ++c) {
    const int ck = c * 32;
    // V + bias issues first (global; longest latency to use)
    bf16x8 vb[4];
#pragma unroll
    for (int df = 0; df < 4; ++df)
      vb[df] = *(const bf16x8*)&VTg[base + (size_t)(df * 16 + l15) * 256 + ck + lg * 8];
    ushort4 bbf[2][4];
#pragma unroll
    for (int kr = 0; kr < 2; ++kr)
#pragma unroll
      for (int qi = 0; qi < 4; ++qi)
        bbf[kr][qi] = *(const ushort4*)&biasbf[(q0 + qi * 16 + l15) * 256 + ck + kr * 16 + lg * 4];
    // K fragments from LDS (swizzled granule)
    bf16x8 kf[2][2];
#pragma unroll
    for (int kr = 0; kr < 2; ++kr)
#pragma unroll
      for (int kc = 0; kc < 2; ++kc) {
        const int row = ck + kr * 16 + l15;
        const int g = (kc * 4 + lg) ^ (row & 7);
        kf[kr][kc] = *(const bf16x8*)&Ks[row * 64 + g * 8];
      }
    // S^T chunk [32k x 64q] = mfma(K, Q)
    f32x4 s[2][4] = {};
#pragma unroll
    for (int kr = 0; kr < 2; ++kr)
#pragma unroll
      for (int qi = 0; qi < 4; ++qi)
#pragma unroll
        for (int kc = 0; kc < 2; ++kc)
          s[kr][qi] = __builtin_amdgcn_mfma_f32_16x16x32_bf16(kf[kr][kc], qfr[qi][kc], s[kr][qi], 0, 0, 0);

    // + bias (Q pre-scaled, so no multiply); per-q chunk max
    float cmax[4];
#pragma unroll
    for (int qi = 0; qi < 4; ++qi) cmax[qi] = -1e30f;
#pragma unroll
    for (int kr = 0; kr < 2; ++kr)
#pragma unroll
      for (int qi = 0; qi < 4; ++qi) {
        const unsigned short* bp = (const unsigned short*)&bbf[kr][qi];
#pragma unroll
        for (int r = 0; r < 4; ++r) {
          float v = s[kr][qi][r] + bf2f(bp[r]);
          s[kr][qi][r] = v;
          cmax[qi] = fmaxf(cmax[qi], v);
        }
      }
#pragma unroll
    for (int qi = 0; qi < 4; ++qi) {
      cmax[qi] = fmaxf(cmax[qi], __shfl_xor(cmax[qi], 16, 64));
      cmax[qi] = fmaxf(cmax[qi], __shfl_xor(cmax[qi], 32, 64));
    }
    // T13 defer-max: skip rescale when no q-row grew its max by >8
    int defer = 1;
#pragma unroll
    for (int qi = 0; qi < 4; ++qi) defer &= (cmax[qi] - mrow[qi] <= 8.f);
    const int full = !__all(defer);   // wave-uniform
    float resc[4];
#pragma unroll
    for (int qi = 0; qi < 4; ++qi) {
      if (full) {
        float mn = fmaxf(mrow[qi], cmax[qi]);
        resc[qi] = __expf(mrow[qi] - mn);
        mrow[qi] = mn;
      } else resc[qi] = 1.f;
    }
    float csum[4];
#pragma unroll
    for (int qi = 0; qi < 4; ++qi) csum[qi] = 0.f;
#pragma unroll
    for (int kr = 0; kr < 2; ++kr)
#pragma unroll
      for (int qi = 0; qi < 4; ++qi)
#pragma unroll
        for (int r = 0; r < 4; ++r) {
          float e = __expf(s[kr][qi][r] - mrow[qi]);
          s[kr][qi][r] = e;
          csum[qi] += e;
        }
#pragma unroll
    for (int qi = 0; qi < 4; ++qi) {
      csum[qi] += __shfl_xor(csum[qi], 16, 64);
      csum[qi] += __shfl_xor(csum[qi], 32, 64);
      lrow[qi] = lrow[qi] * resc[qi] + csum[qi];
    }
    // P -> LDS transposed to [q][k] (per-wave private), packed b64 writes
#pragma unroll
    for (int kr = 0; kr < 2; ++kr)
#pragma unroll
      for (int qi = 0; qi < 4; ++qi) {
        unsigned long long pk = 0;
#pragma unroll
        for (int r = 0; r < 4; ++r)
          pk |= (unsigned long long)f2bf(s[kr][qi][r]) << (16 * r);
        *(unsigned long long*)&P[wave][qi * 16 + l15][kr * 16 + lg * 4] = pk;
      }
    asm volatile("s_waitcnt lgkmcnt(0)" ::: "memory");
    // O rescale only on the full path
    if (full) {
#pragma unroll
      for (int qrf = 0; qrf < 4; ++qrf)
#pragma unroll
        for (int r = 0; r < 4; ++r) {
          float f = __shfl(resc[qrf], lg * 4 + r, 64);
#pragma unroll
          for (int df = 0; df < 4; ++df) o[qrf][df][r] *= f;
        }
    }
    // PV: A = P[q][k] from LDS, B = V chunk
    bf16x8 pa[4];
#pragma unroll
    for (int qrf = 0; qrf < 4; ++qrf)
      pa[qrf] = *(const bf16x8*)&P[wave][qrf * 16 + l15][lg * 8];
#pragma unroll
    for (int qrf = 0; qrf < 4; ++qrf)
#pragma unroll
      for (int df = 0; df < 4; ++df)
        o[qrf][df] = __builtin_amdgcn_mfma_f32_16x16x32_bf16(pa[qrf], vb[df], o[qrf][df], 0, 0, 0);
  }

  // normalize and write ctx [B,S,E] bf16
#pragma unroll
  for (int qrf = 0; qrf < 4; ++qrf)
#pragma unroll
    for (int r = 0; r < 4; ++r) {
      float li = __shfl(lrow[qrf], lg * 4 + r, 64);
      float inv = 1.0f / li;
      const int q = q0 + qrf * 16 + lg * 4 + r;
#pragma unroll
      for (int df = 0; df < 4; ++df) {
        const int d = df * 16 + l15;
        ctx[((size_t)(bb * 256 + q) * 16 + hh) * 64 + d] = f2bf(o[qrf][df][r] * inv);
      }
    }
}

// ---------------------------------------------------------------- launch
extern "C" void kernel_launch(void* const* d_in, const int* in_sizes, int n_in,
                              void* d_out, int out_size, void* d_ws, size_t ws_size,
                              hipStream_t stream) {
  const float* x  = (const float*)d_in[0];
  const float* wi = (const float*)d_in[1];
  const float* bi = (const float*)d_in[2];
  const float* wo = (const float*)d_in[3];
  const float* bo = (const float*)d_in[4];
  const float* sb = (const float*)d_in[5];
  float* out = (float*)d_out;

  char* ws = (char*)d_ws;
  // ws layout (bytes): x_bf/ctx 33554432 | w_in 6291456 | w_out 2097152 | Q | K | VT
  unsigned short* xbf  = (unsigned short*)(ws);
  unsigned short* winb = (unsigned short*)(ws + 33554432u);
  unsigned short* wob  = (unsigned short*)(ws + 39845888u);
  unsigned short* Qb   = (unsigned short*)(ws + 41943040u);
  unsigned short* Kb   = (unsigned short*)(ws + 75497472u);
  unsigned short* VTb  = (unsigned short*)(ws + 109051904u);
  unsigned short* ctx  = xbf;   // x_bf dead after QKV GEMM; reuse for ctx
  unsigned short* sbbf = winb;  // w_in dead after gemm0; bias-bf16 cvt'd there

  cvt_kernel<<<16384, 256, 0, stream>>>(x, xbf, 16777216);
  cvt_kernel<<<3072, 256, 0, stream>>>(wi, winb, 3145728);
  cvt_kernel<<<1024, 256, 0, stream>>>(wo, wob, 1048576);

  // QKV: M=16384 N=3072 K=1024  (Q pre-scaled by 0.125 in epilogue)
  gemm_bt<0><<<dim3(128, 24), 256, 0, stream>>>(xbf, winb, bi, Qb, Kb, VTb, nullptr, nullptr);

  // bias -> bf16 into the now-dead w_in region (64 blocks, 65536 elems)
  cvt_kernel<<<64, 256, 0, stream>>>(sb, sbbf, 65536);

  // attention: one block per (b,h)
  attn_kernel<<<1024, 256, 0, stream>>>(Qb, Kb, VTb, sbbf, ctx);

  // out-proj + residual: M=16384 N=1024 K=1024
  gemm_bt<1><<<dim3(128, 8), 256, 0, stream>>>(ctx, wob, bo, nullptr, nullptr, nullptr, x, out);
}